// Round 11
// baseline (1423.807 us; speedup 1.0000x reference)
//
#include <hip/hip_runtime.h>
#include <hip/hip_bf16.h>

#define N_NODES 100000
#define N_EDGES 1600000
#define N_GRAPHS 64
#define WNB 192      // blocks per destination-window group (8 groups)
#define BCAP 64      // edge bucket capacity per node (max deg ~40 for Poisson(16))

typedef __attribute__((ext_vector_type(8))) short bf16x8;
typedef __attribute__((ext_vector_type(4))) float f32x4;

__device__ inline float bflo(unsigned u) { return __uint_as_float(u << 16); }
__device__ inline float bfhi(unsigned u) { return __uint_as_float(u & 0xffff0000u); }
__device__ inline unsigned short f2bf(float f) {  // RNE, finite inputs
    unsigned u = __float_as_uint(f);
    return (unsigned short)((u + 0x7fff + ((u >> 16) & 1)) >> 16);
}

// ---------------- bucketed CSR build (no count/scan passes) ----------------

__global__ __launch_bounds__(256) void k_curinit(int* __restrict__ cursor, int n) {
    int i = blockIdx.x * 256 + threadIdx.x;
    if (i < n) cursor[i] = i * BCAP;
}

// windowed fill: scatter confined to 12500-node window per XCD
__global__ __launch_bounds__(256) void k_fillw(const int* __restrict__ ei,
                                               int* __restrict__ cursor,
                                               int* __restrict__ cols, int e) {
    const int w = blockIdx.x & 7;
    const int b = blockIdx.x >> 3;
    const int lo = w * 12500, hi = lo + 12500;
    const int4* s4 = (const int4*)ei;
    const int4* d4 = (const int4*)(ei + e);
    const int n4 = e >> 2;
    for (int i = b * 256 + threadIdx.x; i < n4; i += WNB * 256) {
        int4 d = d4[i];
        int4 s = s4[i];
        if (d.x >= lo && d.x < hi) {
            int p = atomicAdd(&cursor[d.x], 1);
            if (p < d.x * BCAP + BCAP) cols[p] = s.x;
        }
        if (d.y >= lo && d.y < hi) {
            int p = atomicAdd(&cursor[d.y], 1);
            if (p < d.y * BCAP + BCAP) cols[p] = s.y;
        }
        if (d.z >= lo && d.z < hi) {
            int p = atomicAdd(&cursor[d.z], 1);
            if (p < d.z * BCAP + BCAP) cols[p] = s.z;
        }
        if (d.w >= lo && d.w < hi) {
            int p = atomicAdd(&cursor[d.w], 1);
            if (p < d.w * BCAP + BCAP) cols[p] = s.w;
        }
    }
}

// dinv from final cursor: deg = cursor[i] - BCAP*i
__global__ __launch_bounds__(256) void k_dinv(const int* __restrict__ cursor,
                                              float* __restrict__ dinv, int n) {
    int i = blockIdx.x * 256 + threadIdx.x;
    if (i < n) dinv[i] = rsqrtf((float)(cursor[i] - BCAP * i + 1));
}

// ---------------- W convert + transpose (all 5 layers, one launch) ----------------

__global__ __launch_bounds__(256) void k_wconv5(const float* __restrict__ W1,
                                                const float* __restrict__ W2,
                                                const float* __restrict__ W3,
                                                const float* __restrict__ W4,
                                                const float* __restrict__ W5,
                                                unsigned short* __restrict__ wt1,
                                                unsigned short* __restrict__ wt2,
                                                unsigned short* __restrict__ wt3,
                                                unsigned short* __restrict__ wt4,
                                                unsigned short* __restrict__ wt5) {
    int i = blockIdx.x * 256 + threadIdx.x;
    const float* W; unsigned short* WT; int FI, FO, j;
    if (i < 16384)      { W = W1; WT = wt1; FI = 128; FO = 128; j = i; }
    else if (i < 32768) { W = W2; WT = wt2; FI = 128; FO = 128; j = i - 16384; }
    else if (i < 49152) { W = W3; WT = wt3; FI = 128; FO = 128; j = i - 32768; }
    else if (i < 57344) { W = W4; WT = wt4; FI = 128; FO = 64;  j = i - 49152; }
    else if (i < 59392) { W = W5; WT = wt5; FI = 64;  FO = 32;  j = i - 57344; }
    else return;
    int n_ = j / FI, k_ = j % FI;
    WT[j] = f2bf(W[(size_t)k_ * FO + n_]);
}

// ---------------- MFMA GEMM: T = A @ WT^T ----------------
// ASM: A is slice-major over K (A_s[k/16][row][16]); OSM: out slice-major over FO.

template <int FI, int FO, bool AF32, bool ASM, bool OSM>
__global__ __launch_bounds__(256) void k_gemm(const void* __restrict__ Ain,
                                              const unsigned short* __restrict__ WT,
                                              unsigned short* __restrict__ Tout, int n) {
    constexpr int NT = FO / 16;
    constexpr int NC = FI / 32;
    const int wave = threadIdx.x >> 6;
    const int lane = threadIdx.x & 63;
    const int m = lane & 15;
    const int q = lane >> 4;
    const int row0 = blockIdx.x * 64 + wave * 16;
    int arow = row0 + m;
    if (arow > n - 1) arow = n - 1;

    f32x4 acc[NT];
    #pragma unroll
    for (int j = 0; j < NT; j++) acc[j] = (f32x4){0.f, 0.f, 0.f, 0.f};

    #pragma unroll
    for (int c = 0; c < NC; c++) {
        const int k0 = c * 32 + q * 8;
        bf16x8 a;
        if constexpr (AF32) {
            const float* ap = (const float*)Ain + (size_t)arow * FI + k0;
            float4 f0 = *reinterpret_cast<const float4*>(ap);
            float4 f1 = *reinterpret_cast<const float4*>(ap + 4);
            a[0] = (short)f2bf(f0.x); a[1] = (short)f2bf(f0.y);
            a[2] = (short)f2bf(f0.z); a[3] = (short)f2bf(f0.w);
            a[4] = (short)f2bf(f1.x); a[5] = (short)f2bf(f1.y);
            a[6] = (short)f2bf(f1.z); a[7] = (short)f2bf(f1.w);
        } else if constexpr (ASM) {
            a = *reinterpret_cast<const bf16x8*>(
                    (const unsigned short*)Ain +
                    ((size_t)(k0 >> 4) * N_NODES + arow) * 16 + (k0 & 15));
        } else {
            a = *reinterpret_cast<const bf16x8*>(
                    (const unsigned short*)Ain + (size_t)arow * FI + k0);
        }
        #pragma unroll
        for (int j = 0; j < NT; j++) {
            bf16x8 b = *reinterpret_cast<const bf16x8*>(
                           WT + (size_t)(j * 16 + m) * FI + k0);
            acc[j] = __builtin_amdgcn_mfma_f32_16x16x32_bf16(a, b, acc[j], 0, 0, 0);
        }
    }

    #pragma unroll
    for (int r = 0; r < 4; r++) {
        int row = row0 + q * 4 + r;
        if (row < n) {
            #pragma unroll
            for (int j = 0; j < NT; j++) {
                if constexpr (OSM)
                    Tout[((size_t)j * N_NODES + row) * 16 + m] = f2bf(acc[j][r]);
                else
                    Tout[(size_t)row * FO + j * 16 + m] = f2bf(acc[j][r]);
            }
        }
    }
}

// ---------------- Sliced aggregation (FA=128, slice-major in/out) ----------------
// blockIdx&7 = slice (pins slice's 3.2MB T region to one XCD's L2 under round-robin
// dispatch). 4 waves/block = 4 nodes; 2 lanes/edge (uint4 = 8 cols), 32 edge slots.

__global__ __launch_bounds__(256) void k_aggs(const unsigned short* __restrict__ T_s,
                                              const int* __restrict__ cursor,
                                              const int* __restrict__ cols,
                                              const float* __restrict__ dinv,
                                              const float* __restrict__ bias,
                                              unsigned short* __restrict__ H_s, int n) {
    const int s = blockIdx.x & 7;
    int node = (blockIdx.x >> 3) * 4 + (threadIdx.x >> 6);
    if (node >= n) return;          // wave-uniform
    node = __builtin_amdgcn_readfirstlane(node);
    const int lane = threadIdx.x & 63;
    const int sub = lane >> 1;      // edge slot 0..31
    const int li  = lane & 1;       // uint4 index within 32B slice row
    const unsigned short* Ts = T_s + (size_t)s * N_NODES * 16;

    const float dn = dinv[node];

    float acc[8];
    #pragma unroll
    for (int k = 0; k < 8; k++) acc[k] = 0.f;

    if (sub == 0) {  // self-loop term (lanes 0,1)
        float dii = dn * dn;
        uint4 u = reinterpret_cast<const uint4*>(Ts + (size_t)node * 16)[li];
        acc[0] = dii * bflo(u.x); acc[1] = dii * bfhi(u.x);
        acc[2] = dii * bflo(u.y); acc[3] = dii * bfhi(u.y);
        acc[4] = dii * bflo(u.z); acc[5] = dii * bfhi(u.z);
        acc[6] = dii * bflo(u.w); acc[7] = dii * bfhi(u.w);
    }

    const int e0 = node * BCAP;
    int e1 = cursor[node];
    if (e1 > e0 + BCAP) e1 = e0 + BCAP;
    for (int e = e0 + sub; e < e1; e += 32) {
        int c = __builtin_nontemporal_load(&cols[e]);
        uint4 tv = reinterpret_cast<const uint4*>(Ts + (size_t)c * 16)[li];
        float w = dinv[c] * dn;
        acc[0] += w * bflo(tv.x); acc[1] += w * bfhi(tv.x);
        acc[2] += w * bflo(tv.y); acc[3] += w * bfhi(tv.y);
        acc[4] += w * bflo(tv.z); acc[5] += w * bfhi(tv.z);
        acc[6] += w * bflo(tv.w); acc[7] += w * bfhi(tv.w);
    }

    #pragma unroll
    for (int off = 2; off < 64; off <<= 1) {
        #pragma unroll
        for (int k = 0; k < 8; k++) acc[k] += __shfl_xor(acc[k], off);
    }

    if (sub == 0) {
        const float* bp = bias + s * 16 + li * 8;
        float4 ba = reinterpret_cast<const float4*>(bp)[0];
        float4 bb = reinterpret_cast<const float4*>(bp)[1];
        float r0 = fmaxf(acc[0] + ba.x, 0.f);
        float r1 = fmaxf(acc[1] + ba.y, 0.f);
        float r2 = fmaxf(acc[2] + ba.z, 0.f);
        float r3 = fmaxf(acc[3] + ba.w, 0.f);
        float r4 = fmaxf(acc[4] + bb.x, 0.f);
        float r5 = fmaxf(acc[5] + bb.y, 0.f);
        float r6 = fmaxf(acc[6] + bb.z, 0.f);
        float r7 = fmaxf(acc[7] + bb.w, 0.f);
        uint4 pk;
        pk.x = (unsigned)f2bf(r0) | ((unsigned)f2bf(r1) << 16);
        pk.y = (unsigned)f2bf(r2) | ((unsigned)f2bf(r3) << 16);
        pk.z = (unsigned)f2bf(r4) | ((unsigned)f2bf(r5) << 16);
        pk.w = (unsigned)f2bf(r6) | ((unsigned)f2bf(r7) << 16);
        reinterpret_cast<uint4*>(H_s + ((size_t)s * N_NODES + node) * 16)[li] = pk;
    }
}

// ---------------- Row-major aggregation (FO<=64), as in R10 ----------------

template <int FO, int UNR>
__global__ __launch_bounds__(256) void k_agg(const unsigned short* __restrict__ T,
                                             const int* __restrict__ cursor,
                                             const int* __restrict__ cols,
                                             const float* __restrict__ dinv,
                                             const float* __restrict__ bias,
                                             unsigned short* __restrict__ Hout, int n) {
    constexpr int LPE = FO / 8;
    constexpr int EPW = 64 / LPE;
    int node = blockIdx.x * 4 + (threadIdx.x >> 6);
    if (node >= n) return;
    node = __builtin_amdgcn_readfirstlane(node);
    const int lane = threadIdx.x & 63;
    const int sub = lane / LPE;
    const int li  = lane % LPE;

    const float dn = dinv[node];

    float acc[8];
    #pragma unroll
    for (int k = 0; k < 8; k++) acc[k] = 0.f;

    if (sub == 0) {
        float dii = dn * dn;
        uint4 u = reinterpret_cast<const uint4*>(T + (size_t)node * FO)[li];
        acc[0] = dii * bflo(u.x); acc[1] = dii * bfhi(u.x);
        acc[2] = dii * bflo(u.y); acc[3] = dii * bfhi(u.y);
        acc[4] = dii * bflo(u.z); acc[5] = dii * bfhi(u.z);
        acc[6] = dii * bflo(u.w); acc[7] = dii * bfhi(u.w);
    }

    const int e0 = node * BCAP;
    int e1 = cursor[node];
    if (e1 > e0 + BCAP) e1 = e0 + BCAP;
    int e = e0 + sub;
    for (; e + (UNR - 1) * EPW < e1; e += UNR * EPW) {
        int cs[UNR]; float ws[UNR]; uint4 tv[UNR];
        #pragma unroll
        for (int u = 0; u < UNR; u++)
            cs[u] = __builtin_nontemporal_load(&cols[e + u * EPW]);
        #pragma unroll
        for (int u = 0; u < UNR; u++)
            tv[u] = reinterpret_cast<const uint4*>(T + (size_t)cs[u] * FO)[li];
        #pragma unroll
        for (int u = 0; u < UNR; u++)
            ws[u] = dinv[cs[u]] * dn;
        #pragma unroll
        for (int u = 0; u < UNR; u++) {
            float w = ws[u];
            acc[0] += w * bflo(tv[u].x); acc[1] += w * bfhi(tv[u].x);
            acc[2] += w * bflo(tv[u].y); acc[3] += w * bfhi(tv[u].y);
            acc[4] += w * bflo(tv[u].z); acc[5] += w * bfhi(tv[u].z);
            acc[6] += w * bflo(tv[u].w); acc[7] += w * bfhi(tv[u].w);
        }
    }
    for (; e < e1; e += EPW) {
        int c = __builtin_nontemporal_load(&cols[e]);
        uint4 tv = reinterpret_cast<const uint4*>(T + (size_t)c * FO)[li];
        float w = dinv[c] * dn;
        acc[0] += w * bflo(tv.x); acc[1] += w * bfhi(tv.x);
        acc[2] += w * bflo(tv.y); acc[3] += w * bfhi(tv.y);
        acc[4] += w * bflo(tv.z); acc[5] += w * bfhi(tv.z);
        acc[6] += w * bflo(tv.w); acc[7] += w * bfhi(tv.w);
    }

    #pragma unroll
    for (int off = LPE; off < 64; off <<= 1) {
        #pragma unroll
        for (int k = 0; k < 8; k++) acc[k] += __shfl_xor(acc[k], off);
    }

    if (sub == 0) {
        float4 ba = reinterpret_cast<const float4*>(bias)[2 * li];
        float4 bb = reinterpret_cast<const float4*>(bias)[2 * li + 1];
        float r0 = fmaxf(acc[0] + ba.x, 0.f);
        float r1 = fmaxf(acc[1] + ba.y, 0.f);
        float r2 = fmaxf(acc[2] + ba.z, 0.f);
        float r3 = fmaxf(acc[3] + ba.w, 0.f);
        float r4 = fmaxf(acc[4] + bb.x, 0.f);
        float r5 = fmaxf(acc[5] + bb.y, 0.f);
        float r6 = fmaxf(acc[6] + bb.z, 0.f);
        float r7 = fmaxf(acc[7] + bb.w, 0.f);
        uint4 pk;
        pk.x = (unsigned)f2bf(r0) | ((unsigned)f2bf(r1) << 16);
        pk.y = (unsigned)f2bf(r2) | ((unsigned)f2bf(r3) << 16);
        pk.z = (unsigned)f2bf(r4) | ((unsigned)f2bf(r5) << 16);
        pk.w = (unsigned)f2bf(r6) | ((unsigned)f2bf(r7) << 16);
        reinterpret_cast<uint4*>(Hout + (size_t)node * FO)[li] = pk;
    }
}

// ---------------- Pool (inline bounds, segmented over sorted batch) + FC ----------------

__global__ __launch_bounds__(256) void k_pool2(const unsigned short* __restrict__ H,
                                               const int* __restrict__ batch,
                                               float* __restrict__ pooled, int n) {
    __shared__ float red0[256], red1[256];
    __shared__ int se[2];
    int g = blockIdx.x;
    int t = threadIdx.x;
    if (t < 2) {
        int target = g + t;
        int lo = 0, hi = n;
        while (lo < hi) {
            int mid = (lo + hi) >> 1;
            if (batch[mid] < target) lo = mid + 1; else hi = mid;
        }
        se[t] = lo;
    }
    __syncthreads();
    int s = se[0], e = se[1];
    int c = t & 15;
    int grp = t >> 4;
    float a0 = 0.f, a1 = 0.f;
    for (int i = s + grp; i < e; i += 16) {
        unsigned u = reinterpret_cast<const unsigned*>(H + (size_t)i * 32)[c];
        a0 += bflo(u); a1 += bfhi(u);
    }
    red0[t] = a0; red1[t] = a1;
    __syncthreads();
    for (int off = 128; off >= 16; off >>= 1) {
        if (t < off) { red0[t] += red0[t + off]; red1[t] += red1[t + off]; }
        __syncthreads();
    }
    if (t < 16) {
        float cnt = fmaxf((float)(e - s), 1.0f);
        pooled[g * 32 + 2 * t]     = red0[t] / cnt;
        pooled[g * 32 + 2 * t + 1] = red1[t] / cnt;
    }
}

__global__ __launch_bounds__(256) void k_fc(const float* __restrict__ pooled,
                                            const float* __restrict__ Wfc,
                                            const float* __restrict__ bfc,
                                            float* __restrict__ out) {
    __shared__ float pl[N_GRAPHS * 32];
    int t = threadIdx.x;
    for (int m = t; m < N_GRAPHS * 32; m += 256) pl[m] = pooled[m];
    __syncthreads();
    for (int o = t; o < N_GRAPHS * 10; o += 256) {
        int g = o / 10, c = o % 10;
        float a = bfc[c];
        #pragma unroll
        for (int k = 0; k < 32; k++) a += pl[g * 32 + k] * Wfc[k * 10 + c];
        out[o] = a;
    }
}

// ---------------- launch ----------------

extern "C" void kernel_launch(void* const* d_in, const int* in_sizes, int n_in,
                              void* d_out, int out_size, void* d_ws, size_t ws_size,
                              hipStream_t stream) {
    const int N = N_NODES, E = N_EDGES;

    const float* x     = (const float*)d_in[0];
    const int*   ei    = (const int*)d_in[1];
    const int*   batch = (const int*)d_in[2];
    const float* W1 = (const float*)d_in[3];  const float* b1 = (const float*)d_in[4];
    const float* W2 = (const float*)d_in[5];  const float* b2 = (const float*)d_in[6];
    const float* W3 = (const float*)d_in[7];  const float* b3 = (const float*)d_in[8];
    const float* W4 = (const float*)d_in[9];  const float* b4 = (const float*)d_in[10];
    const float* W5 = (const float*)d_in[11]; const float* b5 = (const float*)d_in[12];
    const float* Wfc = (const float*)d_in[13]; const float* bfc = (const float*)d_in[14];
    float* out = (float*)d_out;

    char* p = (char*)d_ws;
    auto take = [&](size_t b) { char* q = p; p += (b + 511) & ~(size_t)511; return q; };
    int*   cursor = (int*)take((size_t)N * 4);
    float* dinv   = (float*)take((size_t)N * 4);
    float* pooled = (float*)take(N_GRAPHS * 32 * 4);
    int*   cols   = (int*)take((size_t)N * BCAP * 4);
    unsigned short* wt1 = (unsigned short*)take(128 * 128 * 2);
    unsigned short* wt2 = (unsigned short*)take(128 * 128 * 2);
    unsigned short* wt3 = (unsigned short*)take(128 * 128 * 2);
    unsigned short* wt4 = (unsigned short*)take(128 * 64 * 2);
    unsigned short* wt5 = (unsigned short*)take(64 * 32 * 2);
    unsigned short* Ta  = (unsigned short*)take((size_t)N * 128 * 2);  // bf16 (slice-major for 128)
    unsigned short* Hs  = (unsigned short*)take((size_t)N * 128 * 2);  // bf16 (slice-major for 128)

    const int nb = (N + 255) / 256;

    k_curinit<<<nb, 256, 0, stream>>>(cursor, N);
    k_fillw<<<8 * WNB, 256, 0, stream>>>(ei, cursor, cols, E);
    k_dinv<<<nb, 256, 0, stream>>>(cursor, dinv, N);

    k_wconv5<<<232, 256, 0, stream>>>(W1, W2, W3, W4, W5, wt1, wt2, wt3, wt4, wt5);

    const int gemmb = (N + 63) / 64;
    const int aggb  = (N + 3) / 4;
    const int aggsb = 8 * aggb;

    // layers 1-3: slice-major 128-col pipeline
    k_gemm<128, 128, true,  false, true ><<<gemmb, 256, 0, stream>>>(x, wt1, Ta, N);
    k_aggs<<<aggsb, 256, 0, stream>>>(Ta, cursor, cols, dinv, b1, Hs, N);

    k_gemm<128, 128, false, true,  true ><<<gemmb, 256, 0, stream>>>(Hs, wt2, Ta, N);
    k_aggs<<<aggsb, 256, 0, stream>>>(Ta, cursor, cols, dinv, b2, Hs, N);

    k_gemm<128, 128, false, true,  true ><<<gemmb, 256, 0, stream>>>(Hs, wt3, Ta, N);
    k_aggs<<<aggsb, 256, 0, stream>>>(Ta, cursor, cols, dinv, b3, Hs, N);

    // layer 4: read slice-major H, write row-major 64
    k_gemm<128, 64, false, true,  false><<<gemmb, 256, 0, stream>>>(Hs, wt4, Ta, N);
    k_agg<64, 2><<<aggb, 256, 0, stream>>>(Ta, cursor, cols, dinv, b4, Hs, N);

    // layer 5: row-major throughout
    k_gemm<64, 32, false, false, false><<<gemmb, 256, 0, stream>>>(Hs, wt5, Ta, N);
    k_agg<32, 1><<<aggb, 256, 0, stream>>>(Ta, cursor, cols, dinv, b5, Hs, N);

    k_pool2<<<N_GRAPHS, 256, 0, stream>>>(Hs, batch, pooled, N);
    k_fc<<<1, 256, 0, stream>>>(pooled, Wfc, bfc, out);
}

// Round 12
// 677.071 us; speedup vs baseline: 2.1029x; 2.1029x over previous
//
#include <hip/hip_runtime.h>
#include <hip/hip_bf16.h>

#define N_NODES 100000
#define N_EDGES 1600000
#define N_GRAPHS 64
#define WNB 192      // blocks per destination-window group (8 groups)
#define BCAP 64      // edge bucket capacity per node (max deg ~40 for Poisson(16))

typedef __attribute__((ext_vector_type(8))) short bf16x8;
typedef __attribute__((ext_vector_type(4))) float f32x4;

__device__ inline float bflo(unsigned u) { return __uint_as_float(u << 16); }
__device__ inline float bfhi(unsigned u) { return __uint_as_float(u & 0xffff0000u); }
__device__ inline unsigned short f2bf(float f) {  // RNE, finite inputs
    unsigned u = __float_as_uint(f);
    return (unsigned short)((u + 0x7fff + ((u >> 16) & 1)) >> 16);
}

// ---------------- bucketed CSR build (no count/scan passes) ----------------

__global__ __launch_bounds__(256) void k_curinit(int* __restrict__ cursor, int n) {
    int i = blockIdx.x * 256 + threadIdx.x;
    if (i < n) cursor[i] = i * BCAP;
}

// windowed fill: scatter confined to 12500-node window per XCD
__global__ __launch_bounds__(256) void k_fillw(const int* __restrict__ ei,
                                               int* __restrict__ cursor,
                                               int* __restrict__ cols, int e) {
    const int w = blockIdx.x & 7;
    const int b = blockIdx.x >> 3;
    const int lo = w * 12500, hi = lo + 12500;
    const int4* s4 = (const int4*)ei;
    const int4* d4 = (const int4*)(ei + e);
    const int n4 = e >> 2;
    for (int i = b * 256 + threadIdx.x; i < n4; i += WNB * 256) {
        int4 d = d4[i];
        int4 s = s4[i];
        if (d.x >= lo && d.x < hi) {
            int p = atomicAdd(&cursor[d.x], 1);
            if (p < d.x * BCAP + BCAP) cols[p] = s.x;
        }
        if (d.y >= lo && d.y < hi) {
            int p = atomicAdd(&cursor[d.y], 1);
            if (p < d.y * BCAP + BCAP) cols[p] = s.y;
        }
        if (d.z >= lo && d.z < hi) {
            int p = atomicAdd(&cursor[d.z], 1);
            if (p < d.z * BCAP + BCAP) cols[p] = s.z;
        }
        if (d.w >= lo && d.w < hi) {
            int p = atomicAdd(&cursor[d.w], 1);
            if (p < d.w * BCAP + BCAP) cols[p] = s.w;
        }
    }
}

// dinv from final cursor: deg = cursor[i] - BCAP*i
__global__ __launch_bounds__(256) void k_dinv(const int* __restrict__ cursor,
                                              float* __restrict__ dinv, int n) {
    int i = blockIdx.x * 256 + threadIdx.x;
    if (i < n) dinv[i] = rsqrtf((float)(cursor[i] - BCAP * i + 1));
}

// ---------------- W convert + transpose (all 5 layers, one launch) ----------------

__global__ __launch_bounds__(256) void k_wconv5(const float* __restrict__ W1,
                                                const float* __restrict__ W2,
                                                const float* __restrict__ W3,
                                                const float* __restrict__ W4,
                                                const float* __restrict__ W5,
                                                unsigned short* __restrict__ wt1,
                                                unsigned short* __restrict__ wt2,
                                                unsigned short* __restrict__ wt3,
                                                unsigned short* __restrict__ wt4,
                                                unsigned short* __restrict__ wt5) {
    int i = blockIdx.x * 256 + threadIdx.x;
    const float* W; unsigned short* WT; int FI, FO, j;
    if (i < 16384)      { W = W1; WT = wt1; FI = 128; FO = 128; j = i; }
    else if (i < 32768) { W = W2; WT = wt2; FI = 128; FO = 128; j = i - 16384; }
    else if (i < 49152) { W = W3; WT = wt3; FI = 128; FO = 128; j = i - 32768; }
    else if (i < 57344) { W = W4; WT = wt4; FI = 128; FO = 64;  j = i - 49152; }
    else if (i < 59392) { W = W5; WT = wt5; FI = 64;  FO = 32;  j = i - 57344; }
    else return;
    int n_ = j / FI, k_ = j % FI;
    WT[j] = f2bf(W[(size_t)k_ * FO + n_]);
}

// ---------------- MFMA GEMM: T[N,FO](bf16) = A[N,FI] @ WT^T ----------------
// Epilogue: wave-private LDS transpose -> fully-coalesced uint4 stores
// (lanes 0..FO/8-1 cover one 2*FO-byte row contiguously).

template <int FI, int FO, bool AF32>
__global__ __launch_bounds__(256) void k_gemm(const void* __restrict__ Ain,
                                              const unsigned short* __restrict__ WT,
                                              unsigned short* __restrict__ Tout, int n) {
    constexpr int NT = FO / 16;
    constexpr int NC = FI / 32;
    __shared__ unsigned short tile[4][16][FO];
    const int wave = threadIdx.x >> 6;
    const int lane = threadIdx.x & 63;
    const int m = lane & 15;
    const int q = lane >> 4;
    const int row0 = blockIdx.x * 64 + wave * 16;
    int arow = row0 + m;
    if (arow > n - 1) arow = n - 1;   // clamp for tail block (stores are guarded)

    f32x4 acc[NT];
    #pragma unroll
    for (int j = 0; j < NT; j++) acc[j] = (f32x4){0.f, 0.f, 0.f, 0.f};

    #pragma unroll
    for (int c = 0; c < NC; c++) {
        const int k0 = c * 32 + q * 8;
        bf16x8 a;
        if constexpr (AF32) {
            const float* ap = (const float*)Ain + (size_t)arow * FI + k0;
            float4 f0 = *reinterpret_cast<const float4*>(ap);
            float4 f1 = *reinterpret_cast<const float4*>(ap + 4);
            a[0] = (short)f2bf(f0.x); a[1] = (short)f2bf(f0.y);
            a[2] = (short)f2bf(f0.z); a[3] = (short)f2bf(f0.w);
            a[4] = (short)f2bf(f1.x); a[5] = (short)f2bf(f1.y);
            a[6] = (short)f2bf(f1.z); a[7] = (short)f2bf(f1.w);
        } else {
            a = *reinterpret_cast<const bf16x8*>(
                    (const unsigned short*)Ain + (size_t)arow * FI + k0);
        }
        #pragma unroll
        for (int j = 0; j < NT; j++) {
            bf16x8 b = *reinterpret_cast<const bf16x8*>(
                           WT + (size_t)(j * 16 + m) * FI + k0);
            acc[j] = __builtin_amdgcn_mfma_f32_16x16x32_bf16(a, b, acc[j], 0, 0, 0);
        }
    }

    // C-layout -> wave-private LDS (no barrier: same wave reads it back)
    #pragma unroll
    for (int r = 0; r < 4; r++)
        #pragma unroll
        for (int j = 0; j < NT; j++)
            tile[wave][q * 4 + r][j * 16 + m] = f2bf(acc[j][r]);

    // coalesced store: chunk = 16B; CPR chunks per row; lanes cover rows contiguously
    constexpr int CPR = FO / 8;              // 16 / 8 / 4
    constexpr int ITERS = 16 * CPR / 64;     // 4 / 2 / 1
    #pragma unroll
    for (int it = 0; it < ITERS; it++) {
        int idx = it * 64 + lane;
        int rr = idx / CPR;
        int cc = idx % CPR;
        int row = row0 + rr;
        if (row < n) {
            uint4 v = *reinterpret_cast<const uint4*>(&tile[wave][rr][cc * 8]);
            *reinterpret_cast<uint4*>(&Tout[(size_t)row * FO + cc * 8]) = v;
        }
    }
}

// ---------------- Aggregation: H(bf16) = relu(b + D^-1/2 A D^-1/2 T(bf16)) ----------------
// 1 wave/node, 4 nodes/block. Lane covers 8 cols via uint4; LPE=FO/8 lanes/edge,
// EPW=64/LPE edge slots + unroll UNR => EPW*UNR T-row gathers in flight per wave.

template <int FO, int UNR>
__global__ __launch_bounds__(256) void k_agg(const unsigned short* __restrict__ T,
                                             const int* __restrict__ cursor,
                                             const int* __restrict__ cols,
                                             const float* __restrict__ dinv,
                                             const float* __restrict__ bias,
                                             unsigned short* __restrict__ Hout, int n) {
    constexpr int LPE = FO / 8;     // lanes per edge (8 cols/lane via uint4)
    constexpr int EPW = 64 / LPE;   // concurrent edge slots per wave
    int node = blockIdx.x * 4 + (threadIdx.x >> 6);
    if (node >= n) return;          // wave-uniform
    node = __builtin_amdgcn_readfirstlane(node);
    const int lane = threadIdx.x & 63;
    const int sub = lane / LPE;
    const int li  = lane % LPE;

    const float dn = dinv[node];

    float acc[8];
    #pragma unroll
    for (int k = 0; k < 8; k++) acc[k] = 0.f;

    if (sub == 0) {  // self-loop term
        float dii = dn * dn;
        uint4 u = reinterpret_cast<const uint4*>(T + (size_t)node * FO)[li];
        acc[0] = dii * bflo(u.x); acc[1] = dii * bfhi(u.x);
        acc[2] = dii * bflo(u.y); acc[3] = dii * bfhi(u.y);
        acc[4] = dii * bflo(u.z); acc[5] = dii * bfhi(u.z);
        acc[6] = dii * bflo(u.w); acc[7] = dii * bfhi(u.w);
    }

    const int e0 = node * BCAP;
    int e1 = cursor[node];
    if (e1 > e0 + BCAP) e1 = e0 + BCAP;
    int e = e0 + sub;
    for (; e + (UNR - 1) * EPW < e1; e += UNR * EPW) {
        int cs[UNR]; float ws[UNR]; uint4 tv[UNR];
        #pragma unroll
        for (int u = 0; u < UNR; u++)
            cs[u] = __builtin_nontemporal_load(&cols[e + u * EPW]);
        #pragma unroll
        for (int u = 0; u < UNR; u++)
            tv[u] = reinterpret_cast<const uint4*>(T + (size_t)cs[u] * FO)[li];
        #pragma unroll
        for (int u = 0; u < UNR; u++)
            ws[u] = dinv[cs[u]] * dn;
        #pragma unroll
        for (int u = 0; u < UNR; u++) {
            float w = ws[u];
            acc[0] += w * bflo(tv[u].x); acc[1] += w * bfhi(tv[u].x);
            acc[2] += w * bflo(tv[u].y); acc[3] += w * bfhi(tv[u].y);
            acc[4] += w * bflo(tv[u].z); acc[5] += w * bfhi(tv[u].z);
            acc[6] += w * bflo(tv[u].w); acc[7] += w * bfhi(tv[u].w);
        }
    }
    for (; e < e1; e += EPW) {
        int c = __builtin_nontemporal_load(&cols[e]);
        uint4 tv = reinterpret_cast<const uint4*>(T + (size_t)c * FO)[li];
        float w = dinv[c] * dn;
        acc[0] += w * bflo(tv.x); acc[1] += w * bfhi(tv.x);
        acc[2] += w * bflo(tv.y); acc[3] += w * bfhi(tv.y);
        acc[4] += w * bflo(tv.z); acc[5] += w * bfhi(tv.z);
        acc[6] += w * bflo(tv.w); acc[7] += w * bfhi(tv.w);
    }

    #pragma unroll
    for (int off = LPE; off < 64; off <<= 1) {
        #pragma unroll
        for (int k = 0; k < 8; k++) acc[k] += __shfl_xor(acc[k], off);
    }

    if (sub == 0) {
        float4 ba = reinterpret_cast<const float4*>(bias)[2 * li];
        float4 bb = reinterpret_cast<const float4*>(bias)[2 * li + 1];
        float r0 = fmaxf(acc[0] + ba.x, 0.f);
        float r1 = fmaxf(acc[1] + ba.y, 0.f);
        float r2 = fmaxf(acc[2] + ba.z, 0.f);
        float r3 = fmaxf(acc[3] + ba.w, 0.f);
        float r4 = fmaxf(acc[4] + bb.x, 0.f);
        float r5 = fmaxf(acc[5] + bb.y, 0.f);
        float r6 = fmaxf(acc[6] + bb.z, 0.f);
        float r7 = fmaxf(acc[7] + bb.w, 0.f);
        uint4 pk;
        pk.x = (unsigned)f2bf(r0) | ((unsigned)f2bf(r1) << 16);
        pk.y = (unsigned)f2bf(r2) | ((unsigned)f2bf(r3) << 16);
        pk.z = (unsigned)f2bf(r4) | ((unsigned)f2bf(r5) << 16);
        pk.w = (unsigned)f2bf(r6) | ((unsigned)f2bf(r7) << 16);
        reinterpret_cast<uint4*>(Hout + (size_t)node * FO)[li] = pk;
    }
}

// ---------------- Pool (inline bounds, segmented over sorted batch) + FC ----------------

__global__ __launch_bounds__(256) void k_pool2(const unsigned short* __restrict__ H,
                                               const int* __restrict__ batch,
                                               float* __restrict__ pooled, int n) {
    __shared__ float red0[256], red1[256];
    __shared__ int se[2];
    int g = blockIdx.x;
    int t = threadIdx.x;
    if (t < 2) {  // inline lower_bound(batch, g + t)
        int target = g + t;
        int lo = 0, hi = n;
        while (lo < hi) {
            int mid = (lo + hi) >> 1;
            if (batch[mid] < target) lo = mid + 1; else hi = mid;
        }
        se[t] = lo;
    }
    __syncthreads();
    int s = se[0], e = se[1];
    int c = t & 15;
    int grp = t >> 4;
    float a0 = 0.f, a1 = 0.f;
    for (int i = s + grp; i < e; i += 16) {
        unsigned u = reinterpret_cast<const unsigned*>(H + (size_t)i * 32)[c];
        a0 += bflo(u); a1 += bfhi(u);
    }
    red0[t] = a0; red1[t] = a1;
    __syncthreads();
    for (int off = 128; off >= 16; off >>= 1) {
        if (t < off) { red0[t] += red0[t + off]; red1[t] += red1[t + off]; }
        __syncthreads();
    }
    if (t < 16) {
        float cnt = fmaxf((float)(e - s), 1.0f);
        pooled[g * 32 + 2 * t]     = red0[t] / cnt;
        pooled[g * 32 + 2 * t + 1] = red1[t] / cnt;
    }
}

__global__ __launch_bounds__(256) void k_fc(const float* __restrict__ pooled,
                                            const float* __restrict__ Wfc,
                                            const float* __restrict__ bfc,
                                            float* __restrict__ out) {
    __shared__ float pl[N_GRAPHS * 32];
    int t = threadIdx.x;
    for (int m = t; m < N_GRAPHS * 32; m += 256) pl[m] = pooled[m];
    __syncthreads();
    for (int o = t; o < N_GRAPHS * 10; o += 256) {
        int g = o / 10, c = o % 10;
        float a = bfc[c];
        #pragma unroll
        for (int k = 0; k < 32; k++) a += pl[g * 32 + k] * Wfc[k * 10 + c];
        out[o] = a;
    }
}

// ---------------- launch ----------------

extern "C" void kernel_launch(void* const* d_in, const int* in_sizes, int n_in,
                              void* d_out, int out_size, void* d_ws, size_t ws_size,
                              hipStream_t stream) {
    const int N = N_NODES, E = N_EDGES;

    const float* x     = (const float*)d_in[0];
    const int*   ei    = (const int*)d_in[1];
    const int*   batch = (const int*)d_in[2];
    const float* W1 = (const float*)d_in[3];  const float* b1 = (const float*)d_in[4];
    const float* W2 = (const float*)d_in[5];  const float* b2 = (const float*)d_in[6];
    const float* W3 = (const float*)d_in[7];  const float* b3 = (const float*)d_in[8];
    const float* W4 = (const float*)d_in[9];  const float* b4 = (const float*)d_in[10];
    const float* W5 = (const float*)d_in[11]; const float* b5 = (const float*)d_in[12];
    const float* Wfc = (const float*)d_in[13]; const float* bfc = (const float*)d_in[14];
    float* out = (float*)d_out;

    char* p = (char*)d_ws;
    auto take = [&](size_t b) { char* q = p; p += (b + 511) & ~(size_t)511; return q; };
    int*   cursor = (int*)take((size_t)N * 4);
    float* dinv   = (float*)take((size_t)N * 4);
    float* pooled = (float*)take(N_GRAPHS * 32 * 4);
    int*   cols   = (int*)take((size_t)N * BCAP * 4);
    unsigned short* wt1 = (unsigned short*)take(128 * 128 * 2);
    unsigned short* wt2 = (unsigned short*)take(128 * 128 * 2);
    unsigned short* wt3 = (unsigned short*)take(128 * 128 * 2);
    unsigned short* wt4 = (unsigned short*)take(128 * 64 * 2);
    unsigned short* wt5 = (unsigned short*)take(64 * 32 * 2);
    unsigned short* T   = (unsigned short*)take((size_t)N * 128 * 2);  // bf16
    unsigned short* H   = (unsigned short*)take((size_t)N * 128 * 2);  // bf16

    const int nb = (N + 255) / 256;

    k_curinit<<<nb, 256, 0, stream>>>(cursor, N);
    k_fillw<<<8 * WNB, 256, 0, stream>>>(ei, cursor, cols, E);
    k_dinv<<<nb, 256, 0, stream>>>(cursor, dinv, N);

    k_wconv5<<<232, 256, 0, stream>>>(W1, W2, W3, W4, W5, wt1, wt2, wt3, wt4, wt5);

    const int gemmb = (N + 63) / 64;
    const int aggb  = (N + 3) / 4;

    k_gemm<128, 128, true ><<<gemmb, 256, 0, stream>>>(x, wt1, T, N);
    k_agg<128, 4><<<aggb, 256, 0, stream>>>(T, cursor, cols, dinv, b1, H, N);

    k_gemm<128, 128, false><<<gemmb, 256, 0, stream>>>(H, wt2, T, N);
    k_agg<128, 4><<<aggb, 256, 0, stream>>>(T, cursor, cols, dinv, b2, H, N);

    k_gemm<128, 128, false><<<gemmb, 256, 0, stream>>>(H, wt3, T, N);
    k_agg<128, 4><<<aggb, 256, 0, stream>>>(T, cursor, cols, dinv, b3, H, N);

    k_gemm<128, 64, false><<<gemmb, 256, 0, stream>>>(H, wt4, T, N);
    k_agg<64, 2><<<aggb, 256, 0, stream>>>(T, cursor, cols, dinv, b4, H, N);

    k_gemm<64, 32, false><<<gemmb, 256, 0, stream>>>(H, wt5, T, N);
    k_agg<32, 1><<<aggb, 256, 0, stream>>>(T, cursor, cols, dinv, b5, H, N);

    k_pool2<<<N_GRAPHS, 256, 0, stream>>>(H, batch, pooled, N);
    k_fc<<<1, 256, 0, stream>>>(pooled, Wfc, bfc, out);
}

// Round 13
// 630.939 us; speedup vs baseline: 2.2566x; 1.0731x over previous
//
#include <hip/hip_runtime.h>
#include <hip/hip_bf16.h>

#define N_NODES 100000
#define N_EDGES 1600000
#define N_GRAPHS 64
#define WNB 192      // blocks per destination-window group (8 groups)
#define BCAP 64      // edge bucket capacity per node (max deg ~40 for Poisson(16))

typedef __attribute__((ext_vector_type(8))) short bf16x8;
typedef __attribute__((ext_vector_type(4))) float f32x4;

__device__ inline float bflo(unsigned u) { return __uint_as_float(u << 16); }
__device__ inline float bfhi(unsigned u) { return __uint_as_float(u & 0xffff0000u); }
__device__ inline unsigned short f2bf(float f) {  // RNE, finite inputs
    unsigned u = __float_as_uint(f);
    return (unsigned short)((u + 0x7fff + ((u >> 16) & 1)) >> 16);
}

// ---------------- setup: cursor init + W convert/transpose, one launch ----------------

__global__ __launch_bounds__(256) void k_setup(int* __restrict__ cursor, int n,
                                               const float* __restrict__ W1,
                                               const float* __restrict__ W2,
                                               const float* __restrict__ W3,
                                               const float* __restrict__ W4,
                                               const float* __restrict__ W5,
                                               unsigned short* __restrict__ wt1,
                                               unsigned short* __restrict__ wt2,
                                               unsigned short* __restrict__ wt3,
                                               unsigned short* __restrict__ wt4,
                                               unsigned short* __restrict__ wt5) {
    const int nb = (N_NODES + 255) / 256;
    if ((int)blockIdx.x < nb) {
        int i = blockIdx.x * 256 + threadIdx.x;
        if (i < n) cursor[i] = i * BCAP;
        return;
    }
    int i = (blockIdx.x - nb) * 256 + threadIdx.x;
    const float* W; unsigned short* WT; int FI, FO, j;
    if (i < 16384)      { W = W1; WT = wt1; FI = 128; FO = 128; j = i; }
    else if (i < 32768) { W = W2; WT = wt2; FI = 128; FO = 128; j = i - 16384; }
    else if (i < 49152) { W = W3; WT = wt3; FI = 128; FO = 128; j = i - 32768; }
    else if (i < 57344) { W = W4; WT = wt4; FI = 128; FO = 64;  j = i - 49152; }
    else if (i < 59392) { W = W5; WT = wt5; FI = 64;  FO = 32;  j = i - 57344; }
    else return;
    int n_ = j / FI, k_ = j % FI;
    WT[j] = f2bf(W[(size_t)k_ * FO + n_]);
}

// ---------------- windowed bucket fill (conditional scalar src loads) ----------------

__global__ __launch_bounds__(256) void k_fillw(const int* __restrict__ ei,
                                               int* __restrict__ cursor,
                                               int* __restrict__ cols, int e) {
    const int w = blockIdx.x & 7;
    const int b = blockIdx.x >> 3;
    const int lo = w * 12500, hi = lo + 12500;
    const int4* d4 = (const int4*)(ei + e);
    const int n4 = e >> 2;
    for (int i = b * 256 + threadIdx.x; i < n4; i += WNB * 256) {
        int4 d = d4[i];
        int base = 4 * i;
        if (d.x >= lo && d.x < hi) {
            int p = atomicAdd(&cursor[d.x], 1);
            if (p < d.x * BCAP + BCAP) cols[p] = ei[base];
        }
        if (d.y >= lo && d.y < hi) {
            int p = atomicAdd(&cursor[d.y], 1);
            if (p < d.y * BCAP + BCAP) cols[p] = ei[base + 1];
        }
        if (d.z >= lo && d.z < hi) {
            int p = atomicAdd(&cursor[d.z], 1);
            if (p < d.z * BCAP + BCAP) cols[p] = ei[base + 2];
        }
        if (d.w >= lo && d.w < hi) {
            int p = atomicAdd(&cursor[d.w], 1);
            if (p < d.w * BCAP + BCAP) cols[p] = ei[base + 3];
        }
    }
}

// ---------------- MFMA GEMM layer 1 (f32 A) + dinv prologue ----------------

template <int FI, int FO>
__global__ __launch_bounds__(256) void k_gemm1(const float* __restrict__ Ain,
                                               const unsigned short* __restrict__ WT,
                                               unsigned short* __restrict__ Tout,
                                               const int* __restrict__ cursor,
                                               float* __restrict__ dinv, int n) {
    // dinv prologue (consumed only by later dispatches; no sync needed)
    {
        int gi = blockIdx.x * 256 + threadIdx.x;
        if (gi < n) dinv[gi] = rsqrtf((float)(cursor[gi] - BCAP * gi + 1));
    }
    constexpr int NT = FO / 16;
    constexpr int NC = FI / 32;
    __shared__ unsigned short tile[4][16][FO];
    const int wave = threadIdx.x >> 6;
    const int lane = threadIdx.x & 63;
    const int m = lane & 15;
    const int q = lane >> 4;
    const int row0 = blockIdx.x * 64 + wave * 16;
    int arow = row0 + m;
    if (arow > n - 1) arow = n - 1;

    f32x4 acc[NT];
    #pragma unroll
    for (int j = 0; j < NT; j++) acc[j] = (f32x4){0.f, 0.f, 0.f, 0.f};

    #pragma unroll
    for (int c = 0; c < NC; c++) {
        const int k0 = c * 32 + q * 8;
        const float* ap = Ain + (size_t)arow * FI + k0;
        float4 f0 = *reinterpret_cast<const float4*>(ap);
        float4 f1 = *reinterpret_cast<const float4*>(ap + 4);
        bf16x8 a;
        a[0] = (short)f2bf(f0.x); a[1] = (short)f2bf(f0.y);
        a[2] = (short)f2bf(f0.z); a[3] = (short)f2bf(f0.w);
        a[4] = (short)f2bf(f1.x); a[5] = (short)f2bf(f1.y);
        a[6] = (short)f2bf(f1.z); a[7] = (short)f2bf(f1.w);
        #pragma unroll
        for (int j = 0; j < NT; j++) {
            bf16x8 b = *reinterpret_cast<const bf16x8*>(
                           WT + (size_t)(j * 16 + m) * FI + k0);
            acc[j] = __builtin_amdgcn_mfma_f32_16x16x32_bf16(a, b, acc[j], 0, 0, 0);
        }
    }

    #pragma unroll
    for (int r = 0; r < 4; r++)
        #pragma unroll
        for (int j = 0; j < NT; j++)
            tile[wave][q * 4 + r][j * 16 + m] = f2bf(acc[j][r]);

    constexpr int CPR = FO / 8;
    constexpr int ITERS = 16 * CPR / 64;
    #pragma unroll
    for (int it = 0; it < ITERS; it++) {
        int idx = it * 64 + lane;
        int rr = idx / CPR;
        int cc = idx % CPR;
        int row = row0 + rr;
        if (row < n) {
            uint4 v = *reinterpret_cast<const uint4*>(&tile[wave][rr][cc * 8]);
            *reinterpret_cast<uint4*>(&Tout[(size_t)row * FO + cc * 8]) = v;
        }
    }
}

// ---------------- FUSED agg_l + gemm_{l+1} ----------------
// Block = 256 thr = 4 waves = 16 nodes (4 per wave, sequential). Gather loop is
// byte-identical to R10's k_agg (uint4 lane coverage, EPW*UNR=16 loads in flight).
// h rows -> LDS; one barrier; 4 waves split the 16xFB MFMA tile.

template <int FA, int FB, int UNR>
__global__ __launch_bounds__(256) void k_fused(const unsigned short* __restrict__ T,
                                               const int* __restrict__ cursor,
                                               const int* __restrict__ cols,
                                               const float* __restrict__ dinv,
                                               const float* __restrict__ bias,
                                               const unsigned short* __restrict__ WT,
                                               unsigned short* __restrict__ Tout, int n) {
    constexpr int LPE = FA / 8;     // lanes per edge (8 cols/lane via uint4)
    constexpr int EPW = 64 / LPE;   // concurrent edge slots per wave
    constexpr int STR = FA + 8;     // LDS row stride (bf16), breaks 2-pow aliasing
    __shared__ unsigned short hrow[16][STR];

    const int w = threadIdx.x >> 6;
    const int lane = threadIdx.x & 63;
    const int sub = lane / LPE;
    const int li  = lane % LPE;
    const int node0 = blockIdx.x * 16;

    // ---- phase 1: gather 4 nodes per wave ----
    for (int i = 0; i < 4; i++) {
        const int r = w * 4 + i;
        int node = node0 + r;
        bool valid = node < n;
        if (node > n - 1) node = n - 1;
        node = __builtin_amdgcn_readfirstlane(node);

        const float dn = dinv[node];
        float acc[8];
        #pragma unroll
        for (int k = 0; k < 8; k++) acc[k] = 0.f;

        if (sub == 0) {  // self-loop
            float dii = dn * dn;
            uint4 u = reinterpret_cast<const uint4*>(T + (size_t)node * FA)[li];
            acc[0] = dii * bflo(u.x); acc[1] = dii * bfhi(u.x);
            acc[2] = dii * bflo(u.y); acc[3] = dii * bfhi(u.y);
            acc[4] = dii * bflo(u.z); acc[5] = dii * bfhi(u.z);
            acc[6] = dii * bflo(u.w); acc[7] = dii * bfhi(u.w);
        }

        const int e0 = node * BCAP;
        int e1 = cursor[node];
        if (e1 > e0 + BCAP) e1 = e0 + BCAP;
        int e = e0 + sub;
        for (; e + (UNR - 1) * EPW < e1; e += UNR * EPW) {
            int cs[UNR]; float ws[UNR]; uint4 tv[UNR];
            #pragma unroll
            for (int u = 0; u < UNR; u++)
                cs[u] = __builtin_nontemporal_load(&cols[e + u * EPW]);
            #pragma unroll
            for (int u = 0; u < UNR; u++)
                tv[u] = reinterpret_cast<const uint4*>(T + (size_t)cs[u] * FA)[li];
            #pragma unroll
            for (int u = 0; u < UNR; u++)
                ws[u] = dinv[cs[u]] * dn;
            #pragma unroll
            for (int u = 0; u < UNR; u++) {
                float wv = ws[u];
                acc[0] += wv * bflo(tv[u].x); acc[1] += wv * bfhi(tv[u].x);
                acc[2] += wv * bflo(tv[u].y); acc[3] += wv * bfhi(tv[u].y);
                acc[4] += wv * bflo(tv[u].z); acc[5] += wv * bfhi(tv[u].z);
                acc[6] += wv * bflo(tv[u].w); acc[7] += wv * bfhi(tv[u].w);
            }
        }
        for (; e < e1; e += EPW) {
            int c = __builtin_nontemporal_load(&cols[e]);
            uint4 tv = reinterpret_cast<const uint4*>(T + (size_t)c * FA)[li];
            float wv = dinv[c] * dn;
            acc[0] += wv * bflo(tv.x); acc[1] += wv * bfhi(tv.x);
            acc[2] += wv * bflo(tv.y); acc[3] += wv * bfhi(tv.y);
            acc[4] += wv * bflo(tv.z); acc[5] += wv * bfhi(tv.z);
            acc[6] += wv * bflo(tv.w); acc[7] += wv * bfhi(tv.w);
        }

        #pragma unroll
        for (int off = LPE; off < 64; off <<= 1) {
            #pragma unroll
            for (int k = 0; k < 8; k++) acc[k] += __shfl_xor(acc[k], off);
        }

        if (sub == 0) {
            uint4 pk = {0u, 0u, 0u, 0u};
            if (valid) {
                float4 ba = reinterpret_cast<const float4*>(bias)[2 * li];
                float4 bb = reinterpret_cast<const float4*>(bias)[2 * li + 1];
                float r0 = fmaxf(acc[0] + ba.x, 0.f);
                float r1 = fmaxf(acc[1] + ba.y, 0.f);
                float r2 = fmaxf(acc[2] + ba.z, 0.f);
                float r3 = fmaxf(acc[3] + ba.w, 0.f);
                float r4 = fmaxf(acc[4] + bb.x, 0.f);
                float r5 = fmaxf(acc[5] + bb.y, 0.f);
                float r6 = fmaxf(acc[6] + bb.z, 0.f);
                float r7 = fmaxf(acc[7] + bb.w, 0.f);
                pk.x = (unsigned)f2bf(r0) | ((unsigned)f2bf(r1) << 16);
                pk.y = (unsigned)f2bf(r2) | ((unsigned)f2bf(r3) << 16);
                pk.z = (unsigned)f2bf(r4) | ((unsigned)f2bf(r5) << 16);
                pk.w = (unsigned)f2bf(r6) | ((unsigned)f2bf(r7) << 16);
            }
            *reinterpret_cast<uint4*>(&hrow[r][li * 8]) = pk;
        }
    }

    __syncthreads();

    // ---- phase 2: 16xFB tile = h(16xFA) @ WT^T, 16-col tiles round-robin over waves ----
    constexpr int NTILES = FB / 16;
    constexpr int NC = FA / 32;
    const int m = lane & 15;
    const int q = lane >> 4;

    for (int j = w; j < NTILES; j += 4) {
        f32x4 acc = (f32x4){0.f, 0.f, 0.f, 0.f};
        #pragma unroll
        for (int c = 0; c < NC; c++) {
            const int k0 = c * 32 + q * 8;
            bf16x8 a = *reinterpret_cast<const bf16x8*>(&hrow[m][k0]);
            bf16x8 b = *reinterpret_cast<const bf16x8*>(
                           WT + (size_t)(j * 16 + m) * FA + k0);
            acc = __builtin_amdgcn_mfma_f32_16x16x32_bf16(a, b, acc, 0, 0, 0);
        }
        #pragma unroll
        for (int r = 0; r < 4; r++) {
            int row = node0 + q * 4 + r;
            if (row < n)
                Tout[(size_t)row * FB + j * 16 + m] = f2bf(acc[r]);
        }
    }
}

// ---------------- final aggregation (FO=32) ----------------

template <int FO, int UNR>
__global__ __launch_bounds__(256) void k_agg(const unsigned short* __restrict__ T,
                                             const int* __restrict__ cursor,
                                             const int* __restrict__ cols,
                                             const float* __restrict__ dinv,
                                             const float* __restrict__ bias,
                                             unsigned short* __restrict__ Hout, int n) {
    constexpr int LPE = FO / 8;
    constexpr int EPW = 64 / LPE;
    int node = blockIdx.x * 4 + (threadIdx.x >> 6);
    if (node >= n) return;
    node = __builtin_amdgcn_readfirstlane(node);
    const int lane = threadIdx.x & 63;
    const int sub = lane / LPE;
    const int li  = lane % LPE;

    const float dn = dinv[node];

    float acc[8];
    #pragma unroll
    for (int k = 0; k < 8; k++) acc[k] = 0.f;

    if (sub == 0) {
        float dii = dn * dn;
        uint4 u = reinterpret_cast<const uint4*>(T + (size_t)node * FO)[li];
        acc[0] = dii * bflo(u.x); acc[1] = dii * bfhi(u.x);
        acc[2] = dii * bflo(u.y); acc[3] = dii * bfhi(u.y);
        acc[4] = dii * bflo(u.z); acc[5] = dii * bfhi(u.z);
        acc[6] = dii * bflo(u.w); acc[7] = dii * bfhi(u.w);
    }

    const int e0 = node * BCAP;
    int e1 = cursor[node];
    if (e1 > e0 + BCAP) e1 = e0 + BCAP;
    int e = e0 + sub;
    for (; e + (UNR - 1) * EPW < e1; e += UNR * EPW) {
        int cs[UNR]; float ws[UNR]; uint4 tv[UNR];
        #pragma unroll
        for (int u = 0; u < UNR; u++)
            cs[u] = __builtin_nontemporal_load(&cols[e + u * EPW]);
        #pragma unroll
        for (int u = 0; u < UNR; u++)
            tv[u] = reinterpret_cast<const uint4*>(T + (size_t)cs[u] * FO)[li];
        #pragma unroll
        for (int u = 0; u < UNR; u++)
            ws[u] = dinv[cs[u]] * dn;
        #pragma unroll
        for (int u = 0; u < UNR; u++) {
            float wv = ws[u];
            acc[0] += wv * bflo(tv[u].x); acc[1] += wv * bfhi(tv[u].x);
            acc[2] += wv * bflo(tv[u].y); acc[3] += wv * bfhi(tv[u].y);
            acc[4] += wv * bflo(tv[u].z); acc[5] += wv * bfhi(tv[u].z);
            acc[6] += wv * bflo(tv[u].w); acc[7] += wv * bfhi(tv[u].w);
        }
    }
    for (; e < e1; e += EPW) {
        int c = __builtin_nontemporal_load(&cols[e]);
        uint4 tv = reinterpret_cast<const uint4*>(T + (size_t)c * FO)[li];
        float wv = dinv[c] * dn;
        acc[0] += wv * bflo(tv.x); acc[1] += wv * bfhi(tv.x);
        acc[2] += wv * bflo(tv.y); acc[3] += wv * bfhi(tv.y);
        acc[4] += wv * bflo(tv.z); acc[5] += wv * bfhi(tv.z);
        acc[6] += wv * bflo(tv.w); acc[7] += wv * bfhi(tv.w);
    }

    #pragma unroll
    for (int off = LPE; off < 64; off <<= 1) {
        #pragma unroll
        for (int k = 0; k < 8; k++) acc[k] += __shfl_xor(acc[k], off);
    }

    if (sub == 0) {
        float4 ba = reinterpret_cast<const float4*>(bias)[2 * li];
        float4 bb = reinterpret_cast<const float4*>(bias)[2 * li + 1];
        float r0 = fmaxf(acc[0] + ba.x, 0.f);
        float r1 = fmaxf(acc[1] + ba.y, 0.f);
        float r2 = fmaxf(acc[2] + ba.z, 0.f);
        float r3 = fmaxf(acc[3] + ba.w, 0.f);
        float r4 = fmaxf(acc[4] + bb.x, 0.f);
        float r5 = fmaxf(acc[5] + bb.y, 0.f);
        float r6 = fmaxf(acc[6] + bb.z, 0.f);
        float r7 = fmaxf(acc[7] + bb.w, 0.f);
        uint4 pk;
        pk.x = (unsigned)f2bf(r0) | ((unsigned)f2bf(r1) << 16);
        pk.y = (unsigned)f2bf(r2) | ((unsigned)f2bf(r3) << 16);
        pk.z = (unsigned)f2bf(r4) | ((unsigned)f2bf(r5) << 16);
        pk.w = (unsigned)f2bf(r6) | ((unsigned)f2bf(r7) << 16);
        reinterpret_cast<uint4*>(Hout + (size_t)node * FO)[li] = pk;
    }
}

// ---------------- Pool + FC fused (per-graph FC needs only its own pooled row) ----------------

__global__ __launch_bounds__(256) void k_poolfc(const unsigned short* __restrict__ H,
                                                const int* __restrict__ batch,
                                                const float* __restrict__ Wfc,
                                                const float* __restrict__ bfc,
                                                float* __restrict__ out, int n) {
    __shared__ float red0[256], red1[256];
    __shared__ float pl[32];
    __shared__ int se[2];
    int g = blockIdx.x;
    int t = threadIdx.x;
    if (t < 2) {  // inline lower_bound(batch, g + t)
        int target = g + t;
        int lo = 0, hi = n;
        while (lo < hi) {
            int mid = (lo + hi) >> 1;
            if (batch[mid] < target) lo = mid + 1; else hi = mid;
        }
        se[t] = lo;
    }
    __syncthreads();
    int s = se[0], e = se[1];
    int c = t & 15;
    int grp = t >> 4;
    float a0 = 0.f, a1 = 0.f;
    for (int i = s + grp; i < e; i += 16) {
        unsigned u = reinterpret_cast<const unsigned*>(H + (size_t)i * 32)[c];
        a0 += bflo(u); a1 += bfhi(u);
    }
    red0[t] = a0; red1[t] = a1;
    __syncthreads();
    for (int off = 128; off >= 16; off >>= 1) {
        if (t < off) { red0[t] += red0[t + off]; red1[t] += red1[t + off]; }
        __syncthreads();
    }
    if (t < 16) {
        float cnt = fmaxf((float)(e - s), 1.0f);
        pl[2 * t]     = red0[t] / cnt;
        pl[2 * t + 1] = red1[t] / cnt;
    }
    __syncthreads();
    if (t < 10) {
        float a = bfc[t];
        #pragma unroll
        for (int k = 0; k < 32; k++) a += pl[k] * Wfc[k * 10 + t];
        out[g * 10 + t] = a;
    }
}

// ---------------- launch ----------------

extern "C" void kernel_launch(void* const* d_in, const int* in_sizes, int n_in,
                              void* d_out, int out_size, void* d_ws, size_t ws_size,
                              hipStream_t stream) {
    const int N = N_NODES, E = N_EDGES;

    const float* x     = (const float*)d_in[0];
    const int*   ei    = (const int*)d_in[1];
    const int*   batch = (const int*)d_in[2];
    const float* W1 = (const float*)d_in[3];  const float* b1 = (const float*)d_in[4];
    const float* W2 = (const float*)d_in[5];  const float* b2 = (const float*)d_in[6];
    const float* W3 = (const float*)d_in[7];  const float* b3 = (const float*)d_in[8];
    const float* W4 = (const float*)d_in[9];  const float* b4 = (const float*)d_in[10];
    const float* W5 = (const float*)d_in[11]; const float* b5 = (const float*)d_in[12];
    const float* Wfc = (const float*)d_in[13]; const float* bfc = (const float*)d_in[14];
    float* out = (float*)d_out;

    char* p = (char*)d_ws;
    auto take = [&](size_t b) { char* q = p; p += (b + 511) & ~(size_t)511; return q; };
    int*   cursor = (int*)take((size_t)N * 4);
    float* dinv   = (float*)take((size_t)N * 4);
    int*   cols   = (int*)take((size_t)N * BCAP * 4);
    unsigned short* wt1 = (unsigned short*)take(128 * 128 * 2);
    unsigned short* wt2 = (unsigned short*)take(128 * 128 * 2);
    unsigned short* wt3 = (unsigned short*)take(128 * 128 * 2);
    unsigned short* wt4 = (unsigned short*)take(128 * 64 * 2);
    unsigned short* wt5 = (unsigned short*)take(64 * 32 * 2);
    unsigned short* Ta  = (unsigned short*)take((size_t)N * 128 * 2);  // bf16
    unsigned short* Tb  = (unsigned short*)take((size_t)N * 128 * 2);  // bf16

    const int nb = (N + 255) / 256;              // 391
    const int gemmb = (N + 63) / 64;             // 1563
    const int fusedb = (N + 15) / 16;            // 6250
    const int aggb  = (N + 3) / 4;               // 25000

    k_setup<<<nb + 232, 256, 0, stream>>>(cursor, N, W1, W2, W3, W4, W5,
                                          wt1, wt2, wt3, wt4, wt5);
    k_fillw<<<8 * WNB, 256, 0, stream>>>(ei, cursor, cols, E);

    // T1 = x @ W1 (+ dinv prologue)
    k_gemm1<128, 128><<<gemmb, 256, 0, stream>>>(x, wt1, Ta, cursor, dinv, N);
    // F1: h1 = relu(agg T1 + b1); T2 = h1 @ W2
    k_fused<128, 128, 4><<<fusedb, 256, 0, stream>>>(Ta, cursor, cols, dinv, b1, wt2, Tb, N);
    // F2: T3 = relu(agg T2 + b2) @ W3
    k_fused<128, 128, 4><<<fusedb, 256, 0, stream>>>(Tb, cursor, cols, dinv, b2, wt3, Ta, N);
    // F3: T4 = relu(agg T3 + b3) @ W4   (FB=64)
    k_fused<128, 64, 4><<<fusedb, 256, 0, stream>>>(Ta, cursor, cols, dinv, b3, wt4, Tb, N);
    // F4: T5 = relu(agg T4 + b4) @ W5   (FA=64, FB=32)
    k_fused<64, 32, 2><<<fusedb, 256, 0, stream>>>(Tb, cursor, cols, dinv, b4, wt5, Ta, N);
    // final aggregation -> H5 (into Tb)
    k_agg<32, 1><<<aggb, 256, 0, stream>>>(Ta, cursor, cols, dinv, b5, Tb, N);

    k_poolfc<<<N_GRAPHS, 256, 0, stream>>>(Tb, batch, Wfc, bfc, out, N);
}